// Round 3
// baseline (180.882 us; speedup 1.0000x reference)
//
#include <hip/hip_runtime.h>

// Reference collapse (verified absmax=0.0 in a prior round):
//   A[b,n,h,l] = 1/256 exactly (softmax of a constant vector; k is all-ones)
//   V[b, n*16+h, d] = (1/256) * sum_{l=0}^{15} v[b, l*256 + n, d]   (independent of h)
// q is never read. Pure memory-bound: read 64 MiB (v), write 192 MiB (V 64 + A 128).
// Roofline: 268 MB / ~6.7 TB/s ~= 41 us for this kernel.
//
// R6: back to the known-good R3 two-role structure (fused single-role kernel
// SIGABRT'd twice on anomalous containers). Changes vs R3:
//   - grid 3072 -> 2048 blocks: exactly one dispatch wave at 8 blocks/CU,
//     no backfill tail.
//   - A-region now 1024 blocks x 32 float4/thread (512B/thread), matching the
//     V-threads' 256B read + 256B write. Equal per-thread byte traffic.
//   - roles interleaved by block parity (even=V, odd=A) so every CU carries a
//     mix of strided-read waves and pure-store waves; the A stores keep the
//     bus busy inside the V loads' latency shadow.

#define BB 8
#define LL 4096
#define DD 512
#define HH 16
#define NN 256           // LL / HH
#define D4 (DD / 4)      // 128 float4 per row

typedef float vfloat4 __attribute__((ext_vector_type(4)));

__global__ __launch_bounds__(256) void attn_collapse_kernel(
    const vfloat4* __restrict__ v, vfloat4* __restrict__ out)
{
    const int blk  = blockIdx.x;       // 0 .. 2047
    const int half = blk >> 1;         // 0 .. 1023  (role-local block id)

    if ((blk & 1) == 0) {
        // ---- V role: 1024 blocks, 1 thread per (b, n, d4) ----
        const int t  = half * 256 + threadIdx.x;  // 0 .. 262143
        const int d4 = t & (D4 - 1);              // 0 .. 127
        const int n  = (t >> 7) & (NN - 1);       // 0 .. 255
        const int b  = t >> 15;                   // 0 .. 7

        // v float4 index: (b*4096 + l*256 + n)*128 + d4, stride over l = NN*D4
        const vfloat4* vp = v + ((size_t)(b * LL + n) * D4 + d4);
        vfloat4 acc = (vfloat4)(0.f, 0.f, 0.f, 0.f);
#pragma unroll
        for (int l = 0; l < HH; ++l) {
            vfloat4 x = __builtin_nontemporal_load(&vp[(size_t)l * NN * D4]);
            acc += x;
        }
        acc *= (1.0f / 256.0f);

        // out V float4 index: (b*4096 + n*16 + h)*128 + d4, stride over h = D4
        vfloat4* op = out + ((size_t)(b * LL + n * HH) * D4 + d4);
#pragma unroll
        for (int h = 0; h < HH; ++h) {
            __builtin_nontemporal_store(acc, &op[(size_t)h * D4]);
        }
    } else {
        // ---- A role: 1024 blocks, 32 float4 per thread ----
        // A region: starts at float4 offset BB*LL*D4 = 4,194,304;
        // spans BB*NN*HH*NN/4 = 8,388,608 float4 (128 MiB)
        const size_t a_base   = (size_t)BB * LL * D4;
        const size_t a_count  = (size_t)BB * NN * HH * NN / 4;
        const size_t nthreads = 1024u * 256u;     // 262,144 -> 32 f4 each, exact
        size_t t = (size_t)half * 256 + threadIdx.x;
        const vfloat4 val = (vfloat4)(1.0f / 256.0f, 1.0f / 256.0f,
                                      1.0f / 256.0f, 1.0f / 256.0f);
        for (size_t i = t; i < a_count; i += nthreads) {
            __builtin_nontemporal_store(val, &out[a_base + i]);
        }
    }
}

extern "C" void kernel_launch(void* const* d_in, const int* in_sizes, int n_in,
                              void* d_out, int out_size, void* d_ws, size_t ws_size,
                              hipStream_t stream) {
    // d_in[0] = q (unused), d_in[1] = v
    const vfloat4* v = (const vfloat4*)d_in[1];
    vfloat4* out = (vfloat4*)d_out;
    attn_collapse_kernel<<<dim3(2048), dim3(256), 0, stream>>>(v, out);
}